// Round 2
// baseline (514.545 us; speedup 1.0000x reference)
//
#include <hip/hip_runtime.h>
#include <stdint.h>
#include <stddef.h>

typedef __attribute__((ext_vector_type(8))) _Float16 f16x8;
typedef __attribute__((ext_vector_type(4))) float f32x4;

#define D_IN 153
#define B_ROWS 262144
#define M_TILE 64
#define XB_STRIDE 168
#define G1_STRIDE 68
#define G2_STRIDE 33
#define H1_STRIDE 136
#define H2_STRIDE 72

// swizzled f16 weight layout offsets (in u16 elements, all multiples of 512)
#define OFF_WP 0
#define SZ_WP (5*10*512)
#define OFF_WG1 (OFF_WP + SZ_WP)
#define SZ_WG1 (5*4*512)
#define OFF_WE1 (OFF_WG1 + SZ_WG1)
#define SZ_WE1 (8*5*8*512)
#define OFF_WE2 (OFF_WE1 + SZ_WE1)
#define SZ_WE2 (8*4*4*512)
#define OFF_WE3 (OFF_WE2 + SZ_WE2)
#define SZ_WE3 (8*2*512)
#define TOTAL_W (OFF_WE3 + SZ_WE3)   // 273408 u16 = 546816 B

__device__ __forceinline__ unsigned short f2h(float f) {
    _Float16 h = (_Float16)f;                 // v_cvt_f16_f32, RNE
    union { _Float16 h; unsigned short u; } v; v.h = h;
    return v.u;
}
__device__ __forceinline__ float h2f(unsigned short u) {
    union { unsigned short u; _Float16 h; } v; v.u = u;
    return (float)v.h;
}

__device__ __forceinline__ f32x4 mfma16(f16x8 a, f16x8 b, f32x4 c) {
    return __builtin_amdgcn_mfma_f32_16x16x32_f16(a, b, c, 0, 0, 0);
}

// A-fragment from LDS: A[m = lane&15][k = quad*8 + j], 16B contiguous per lane
__device__ __forceinline__ f16x8 ldsA(const unsigned short* buf, int stride,
                                      int m0, int k0, int lane) {
    int row = m0 + (lane & 15);
    int col = k0 + (lane >> 4) * 8;
    return *(const f16x8*)(buf + row * stride + col);
}
// B-fragment from pre-swizzled global: tile of 64 lanes x 16B
__device__ __forceinline__ f16x8 ldB(const unsigned short* ws, int tile, int lane) {
    return *(const f16x8*)(ws + (size_t)tile * 512 + lane * 8);
}

// ---------------------------------------------------------------------------
// Weight conversion: fp32 -> fp16 in MFMA B-fragment-swizzled layout.
// For a [K][N] weight: tile (kt,nt) holds B[kt*32+quad*8+j][nt*16+nl] at
// flat u16 index (tile*64 + lane)*8 + j, lane = quad*16+nl. Pads are zero.
// ---------------------------------------------------------------------------
__global__ __launch_bounds__(256) void convert_weights(
        const float* __restrict__ Wp, const float* __restrict__ Wg1,
        const float* __restrict__ We1, const float* __restrict__ We2,
        const float* __restrict__ We3, unsigned short* __restrict__ ws) {
    int idx = blockIdx.x * 256 + threadIdx.x;
    if (idx >= TOTAL_W) return;
    int j = idx & 7;
    int lane = (idx >> 3) & 63;
    int t = idx >> 9;
    int quad = lane >> 4, nl = lane & 15;
    int kin = quad * 8 + j;
    float val = 0.f;
    if (idx < OFF_WG1) {                 // Wp [153][153], Kp=160 Np=160
        int kt = t / 10, nt = t % 10;
        int k = kt * 32 + kin, n = nt * 16 + nl;
        if (k < 153 && n < 153) val = Wp[k * 153 + n];
    } else if (idx < OFF_WE1) {          // Wg1 [153][64]
        int tt = t - (OFF_WG1 >> 9);
        int kt = tt / 4, nt = tt % 4;
        int k = kt * 32 + kin, n = nt * 16 + nl;
        if (k < 153) val = Wg1[k * 64 + n];
    } else if (idx < OFF_WE2) {          // We1 [8][153][128]
        int tt = t - (OFF_WE1 >> 9);
        int e = tt / 40, r = tt % 40, kt = r / 8, nt = r % 8;
        int k = kt * 32 + kin, n = nt * 16 + nl;
        if (k < 153) val = We1[((size_t)e * 153 + k) * 128 + n];
    } else if (idx < OFF_WE3) {          // We2 [8][128][64]
        int tt = t - (OFF_WE2 >> 9);
        int e = tt / 16, r = tt % 16, kt = r / 4, nt = r % 4;
        int k = kt * 32 + kin, n = nt * 16 + nl;
        val = We2[((size_t)e * 128 + k) * 64 + n];
    } else {                             // We3 [8][64][8], Np=16 (cols 8..15 zero)
        int tt = t - (OFF_WE3 >> 9);
        int e = tt / 2, kt = tt % 2;
        int k = kt * 32 + kin, n = nl;
        if (n < 8) val = We3[((size_t)e * 64 + k) * 8 + n];
    }
    ws[idx] = f2h(val);
}

// ---------------------------------------------------------------------------
// Fused MoE kernel: one block = 64 rows, 4 waves.
// ---------------------------------------------------------------------------
__global__ __launch_bounds__(256, 2) void moe_main(
        const float* __restrict__ x,
        const float* __restrict__ ln_in_g, const float* __restrict__ ln_in_b,
        const float* __restrict__ bp,
        const float* __restrict__ bg1,
        const float* __restrict__ Wg2, const float* __restrict__ bg2,
        const float* __restrict__ Wg3, const float* __restrict__ bg3,
        const float* __restrict__ be1, const float* __restrict__ be2,
        const float* __restrict__ be3,
        const float* __restrict__ ln_out_g, const float* __restrict__ ln_out_b,
        const unsigned short* __restrict__ wsw,
        float* __restrict__ out) {
    const int tid = threadIdx.x;
    const int wave = tid >> 6, lane = tid & 63;
    const int quad = lane >> 4, nl = lane & 15;
    const size_t rowBase = (size_t)blockIdx.x * M_TILE;

    __shared__ __align__(16) unsigned short xb[M_TILE * XB_STRIDE];  // x_norm f16
    __shared__ __align__(16) unsigned short xp[M_TILE * XB_STRIDE];  // x_proj f16
    __shared__ __align__(16) float gate[M_TILE * 8];
    __shared__ __align__(16) char scratch[26624];
    float* g1 = (float*)scratch;                                   // [64][68] f32
    float* g2 = (float*)(scratch + 17408);                         // [64][33] f32
    unsigned short* h1 = (unsigned short*)scratch;                 // [64][136] f16
    unsigned short* h2 = (unsigned short*)(scratch + 17408);       // [64][72] f16

    const f32x4 fzero = {0.f, 0.f, 0.f, 0.f};

    // ---- Phase 1: input LayerNorm (4 threads per row) ----
    {
        int r = tid >> 2, seg = tid & 3;
        const float* xr = x + (rowBase + r) * (size_t)D_IN;
        float vals[39];
        float s = 0.f, sq = 0.f;
        #pragma unroll
        for (int i = 0; i < 39; i++) {
            int c = seg + i * 4;
            float v = (c < D_IN) ? xr[c] : 0.f;
            vals[i] = v; s += v; sq += v * v;
        }
        s += __shfl_xor(s, 1);  s += __shfl_xor(s, 2);
        sq += __shfl_xor(sq, 1); sq += __shfl_xor(sq, 2);
        float mean = s * (1.f / 153.f);
        float var = sq * (1.f / 153.f) - mean * mean;
        float rstd = rsqrtf(var + 1e-5f);
        #pragma unroll
        for (int i = 0; i < 39; i++) {
            int c = seg + i * 4;
            if (c < D_IN) {
                float v = (vals[i] - mean) * rstd * ln_in_g[c] + ln_in_b[c];
                xb[r * XB_STRIDE + c] = f2h(v);
            }
        }
        if (tid < M_TILE) {
            #pragma unroll
            for (int c = D_IN; c < XB_STRIDE; c++) xb[tid * XB_STRIDE + c] = 0;
        }
    }
    __syncthreads();

    // ---- Phase 2: x_proj = relu(x_norm @ Wp + bp) + x_norm  (M=64,N=160,K=160)
    {
        f32x4 acc[3][4];
        #pragma unroll
        for (int q = 0; q < 3; q++)
            #pragma unroll
            for (int m = 0; m < 4; m++) acc[q][m] = fzero;
        const int nnt = (wave < 2) ? 3 : 2;
        for (int kt = 0; kt < 5; kt++) {
            f16x8 a0 = ldsA(xb, XB_STRIDE, 0,  kt * 32, lane);
            f16x8 a1 = ldsA(xb, XB_STRIDE, 16, kt * 32, lane);
            f16x8 a2 = ldsA(xb, XB_STRIDE, 32, kt * 32, lane);
            f16x8 a3 = ldsA(xb, XB_STRIDE, 48, kt * 32, lane);
            #pragma unroll
            for (int q = 0; q < 3; q++) {
                if (q < nnt) {
                    int nt = wave + 4 * q;
                    f16x8 b = ldB(wsw, (OFF_WP >> 9) + kt * 10 + nt, lane);
                    acc[q][0] = mfma16(a0, b, acc[q][0]);
                    acc[q][1] = mfma16(a1, b, acc[q][1]);
                    acc[q][2] = mfma16(a2, b, acc[q][2]);
                    acc[q][3] = mfma16(a3, b, acc[q][3]);
                }
            }
        }
        #pragma unroll
        for (int q = 0; q < 3; q++) {
            if (q < nnt) {
                int nt = wave + 4 * q;
                int col = nt * 16 + nl;
                float bpv = (col < D_IN) ? bp[col] : 0.f;
                #pragma unroll
                for (int m = 0; m < 4; m++)
                    #pragma unroll
                    for (int i = 0; i < 4; i++) {
                        int row = m * 16 + quad * 4 + i;
                        float v = fmaxf(acc[q][m][i] + bpv, 0.f)
                                  + h2f(xb[row * XB_STRIDE + col]);
                        xp[row * XB_STRIDE + col] = f2h(v);
                    }
            }
        }
        if (tid < M_TILE) {
            #pragma unroll
            for (int c = 160; c < XB_STRIDE; c++) xp[tid * XB_STRIDE + c] = 0;
        }
    }
    __syncthreads();

    // ---- Phase 3: g1 = relu(x_proj @ Wg1 + bg1)  (M=64,N=64,K=160)
    {
        f32x4 acc[4];
        #pragma unroll
        for (int m = 0; m < 4; m++) acc[m] = fzero;
        for (int kt = 0; kt < 5; kt++) {
            f16x8 a0 = ldsA(xp, XB_STRIDE, 0,  kt * 32, lane);
            f16x8 a1 = ldsA(xp, XB_STRIDE, 16, kt * 32, lane);
            f16x8 a2 = ldsA(xp, XB_STRIDE, 32, kt * 32, lane);
            f16x8 a3 = ldsA(xp, XB_STRIDE, 48, kt * 32, lane);
            f16x8 b = ldB(wsw, (OFF_WG1 >> 9) + kt * 4 + wave, lane);
            acc[0] = mfma16(a0, b, acc[0]);
            acc[1] = mfma16(a1, b, acc[1]);
            acc[2] = mfma16(a2, b, acc[2]);
            acc[3] = mfma16(a3, b, acc[3]);
        }
        int col = wave * 16 + nl;
        float bv = bg1[col];
        #pragma unroll
        for (int m = 0; m < 4; m++)
            #pragma unroll
            for (int i = 0; i < 4; i++) {
                int row = m * 16 + quad * 4 + i;
                g1[row * G1_STRIDE + col] = fmaxf(acc[m][i] + bv, 0.f);
            }
    }
    __syncthreads();

    // ---- Phase 4: g2 = relu(g1 @ Wg2 + bg2)  vector (K=64,N=32)
    {
        int r = tid >> 2, c0 = (tid & 3) * 8;
        float s[8];
        #pragma unroll
        for (int c = 0; c < 8; c++) s[c] = bg2[c0 + c];
        for (int k = 0; k < 64; k++) {
            float gv = g1[r * G1_STRIDE + k];
            #pragma unroll
            for (int c = 0; c < 8; c++) s[c] += gv * Wg2[k * 32 + c0 + c];
        }
        #pragma unroll
        for (int c = 0; c < 8; c++) g2[r * G2_STRIDE + c0 + c] = fmaxf(s[c], 0.f);
    }
    __syncthreads();

    // ---- Phase 5: gating logits + softmax, write gating output ----
    if (tid < M_TILE) {
        int r = tid;
        float s[8];
        #pragma unroll
        for (int o = 0; o < 8; o++) s[o] = bg3[o];
        for (int k = 0; k < 32; k++) {
            float gv = g2[r * G2_STRIDE + k];
            #pragma unroll
            for (int o = 0; o < 8; o++) s[o] += gv * Wg3[k * 8 + o];
        }
        float mx = s[0];
        #pragma unroll
        for (int o = 1; o < 8; o++) mx = fmaxf(mx, s[o]);
        float sum = 0.f;
        #pragma unroll
        for (int o = 0; o < 8; o++) { s[o] = __expf(s[o] - mx); sum += s[o]; }
        float inv = 1.f / sum;
        #pragma unroll
        for (int o = 0; o < 8; o++) { s[o] *= inv; gate[r * 8 + o] = s[o]; }
        float* og = out + (size_t)B_ROWS * 8 + (rowBase + r) * 8;
        *(float4*)og       = make_float4(s[0], s[1], s[2], s[3]);
        *(float4*)(og + 4) = make_float4(s[4], s[5], s[6], s[7]);
    }
    __syncthreads();

    // ---- Phase 6: experts ----
    float oacc[4] = {0.f, 0.f, 0.f, 0.f};
    for (int e = 0; e < 8; e++) {
        // We1: h1 = relu(x_proj @ We1[e] + be1[e])  (M=64,N=128,K=160)
        {
            f32x4 acc[2][4];
            #pragma unroll
            for (int q = 0; q < 2; q++)
                #pragma unroll
                for (int m = 0; m < 4; m++) acc[q][m] = fzero;
            for (int kt = 0; kt < 5; kt++) {
                f16x8 a0 = ldsA(xp, XB_STRIDE, 0,  kt * 32, lane);
                f16x8 a1 = ldsA(xp, XB_STRIDE, 16, kt * 32, lane);
                f16x8 a2 = ldsA(xp, XB_STRIDE, 32, kt * 32, lane);
                f16x8 a3 = ldsA(xp, XB_STRIDE, 48, kt * 32, lane);
                int tb = (OFF_WE1 >> 9) + (e * 5 + kt) * 8 + wave * 2;
                f16x8 b0 = ldB(wsw, tb, lane);
                f16x8 b1 = ldB(wsw, tb + 1, lane);
                acc[0][0] = mfma16(a0, b0, acc[0][0]);
                acc[0][1] = mfma16(a1, b0, acc[0][1]);
                acc[0][2] = mfma16(a2, b0, acc[0][2]);
                acc[0][3] = mfma16(a3, b0, acc[0][3]);
                acc[1][0] = mfma16(a0, b1, acc[1][0]);
                acc[1][1] = mfma16(a1, b1, acc[1][1]);
                acc[1][2] = mfma16(a2, b1, acc[1][2]);
                acc[1][3] = mfma16(a3, b1, acc[1][3]);
            }
            #pragma unroll
            for (int q = 0; q < 2; q++) {
                int col = wave * 32 + q * 16 + nl;
                float bv = be1[e * 128 + col];
                #pragma unroll
                for (int m = 0; m < 4; m++)
                    #pragma unroll
                    for (int i = 0; i < 4; i++) {
                        int row = m * 16 + quad * 4 + i;
                        h1[row * H1_STRIDE + col] = f2h(fmaxf(acc[q][m][i] + bv, 0.f));
                    }
            }
        }
        __syncthreads();
        // We2: h2 = relu(h1 @ We2[e] + be2[e])  (M=64,N=64,K=128)
        {
            f32x4 acc[4];
            #pragma unroll
            for (int m = 0; m < 4; m++) acc[m] = fzero;
            for (int kt = 0; kt < 4; kt++) {
                f16x8 a0 = ldsA(h1, H1_STRIDE, 0,  kt * 32, lane);
                f16x8 a1 = ldsA(h1, H1_STRIDE, 16, kt * 32, lane);
                f16x8 a2 = ldsA(h1, H1_STRIDE, 32, kt * 32, lane);
                f16x8 a3 = ldsA(h1, H1_STRIDE, 48, kt * 32, lane);
                f16x8 b = ldB(wsw, (OFF_WE2 >> 9) + (e * 4 + kt) * 4 + wave, lane);
                acc[0] = mfma16(a0, b, acc[0]);
                acc[1] = mfma16(a1, b, acc[1]);
                acc[2] = mfma16(a2, b, acc[2]);
                acc[3] = mfma16(a3, b, acc[3]);
            }
            int col = wave * 16 + nl;
            float bv = be2[e * 64 + col];
            #pragma unroll
            for (int m = 0; m < 4; m++)
                #pragma unroll
                for (int i = 0; i < 4; i++) {
                    int row = m * 16 + quad * 4 + i;
                    h2[row * H2_STRIDE + col] = f2h(fmaxf(acc[m][i] + bv, 0.f));
                }
        }
        __syncthreads();
        // We3 + gated accumulate  (per wave: rows wave*16..+15; M=16,N=16(8),K=64)
        {
            f32x4 acc = fzero;
            #pragma unroll
            for (int kt = 0; kt < 2; kt++) {
                f16x8 a = ldsA(h2, H2_STRIDE, wave * 16, kt * 32, lane);
                f16x8 b = ldB(wsw, (OFF_WE3 >> 9) + e * 2 + kt, lane);
                acc = mfma16(a, b, acc);
            }
            if (nl < 8) {
                float bv = be3[e * 8 + nl];
                #pragma unroll
                for (int i = 0; i < 4; i++) {
                    int row = wave * 16 + quad * 4 + i;
                    oacc[i] += gate[row * 8 + e] * (acc[i] + bv);
                }
            }
        }
        __syncthreads();
    }

    // ---- Phase 7: output LayerNorm over 8 + store ----
    {
        float go = 1.f, bo = 0.f;
        if (nl < 8) { go = ln_out_g[nl]; bo = ln_out_b[nl]; }
        #pragma unroll
        for (int i = 0; i < 4; i++) {
            float v = oacc[i];
            float s = v + __shfl_xor(v, 1);
            s += __shfl_xor(s, 2);
            s += __shfl_xor(s, 4);
            float q2 = v * v;
            float q = q2 + __shfl_xor(q2, 1);
            q += __shfl_xor(q, 2);
            q += __shfl_xor(q, 4);
            float mean = s * 0.125f;
            float var = q * 0.125f - mean * mean;
            float rstd = rsqrtf(var + 1e-5f);
            float ov = (v - mean) * rstd * go + bo;
            if (nl < 8) {
                size_t row = rowBase + wave * 16 + quad * 4 + i;
                out[row * 8 + nl] = ov;
            }
        }
    }
}

extern "C" void kernel_launch(void* const* d_in, const int* in_sizes, int n_in,
                              void* d_out, int out_size, void* d_ws, size_t ws_size,
                              hipStream_t stream) {
    const float* x        = (const float*)d_in[0];
    const float* ln_in_g  = (const float*)d_in[1];
    const float* ln_in_b  = (const float*)d_in[2];
    const float* Wp       = (const float*)d_in[3];
    const float* bp       = (const float*)d_in[4];
    const float* Wg1      = (const float*)d_in[5];
    const float* bg1      = (const float*)d_in[6];
    const float* Wg2      = (const float*)d_in[7];
    const float* bg2      = (const float*)d_in[8];
    const float* Wg3      = (const float*)d_in[9];
    const float* bg3      = (const float*)d_in[10];
    const float* We1      = (const float*)d_in[11];
    const float* be1      = (const float*)d_in[12];
    const float* We2      = (const float*)d_in[13];
    const float* be2      = (const float*)d_in[14];
    const float* We3      = (const float*)d_in[15];
    const float* be3      = (const float*)d_in[16];
    const float* ln_out_g = (const float*)d_in[17];
    const float* ln_out_b = (const float*)d_in[18];
    unsigned short* ws = (unsigned short*)d_ws;
    float* out = (float*)d_out;

    convert_weights<<<TOTAL_W / 256, 256, 0, stream>>>(Wp, Wg1, We1, We2, We3, ws);
    moe_main<<<B_ROWS / M_TILE, 256, 0, stream>>>(
        x, ln_in_g, ln_in_b, bp, bg1, Wg2, bg2, Wg3, bg3,
        be1, be2, be3, ln_out_g, ln_out_b, ws, out);
}

// Round 6
// 474.627 us; speedup vs baseline: 1.0841x; 1.0841x over previous
//
#include <hip/hip_runtime.h>
#include <stdint.h>
#include <stddef.h>

typedef __attribute__((ext_vector_type(8))) _Float16 f16x8;
typedef __attribute__((ext_vector_type(4))) float f32x4;

#define D_IN 153
#define B_ROWS 262144
#define M_TILE 64
#define XB_STRIDE 168
#define G1_STRIDE 68
#define G2_STRIDE 33
#define H1_STRIDE 136
#define H2_STRIDE 72

// swizzled f16 weight layout offsets (in u16 elements, all multiples of 512)
#define OFF_WP 0
#define SZ_WP (5*10*512)
#define OFF_WG1 (OFF_WP + SZ_WP)
#define SZ_WG1 (5*4*512)
#define OFF_WE1 (OFF_WG1 + SZ_WG1)
#define SZ_WE1 (8*5*8*512)
#define OFF_WE2 (OFF_WE1 + SZ_WE1)
#define SZ_WE2 (8*4*4*512)
#define OFF_WE3 (OFF_WE2 + SZ_WE2)
#define SZ_WE3 (8*2*512)
#define TOTAL_W (OFF_WE3 + SZ_WE3)   // 273408 u16 = 546816 B

__device__ __forceinline__ unsigned short f2h(float f) {
    _Float16 h = (_Float16)f;                 // v_cvt_f16_f32, RNE
    union { _Float16 h; unsigned short u; } v; v.h = h;
    return v.u;
}
__device__ __forceinline__ float h2f(unsigned short u) {
    union { unsigned short u; _Float16 h; } v; v.u = u;
    return (float)v.h;
}

__device__ __forceinline__ f32x4 mfma16(f16x8 a, f16x8 b, f32x4 c) {
    return __builtin_amdgcn_mfma_f32_16x16x32_f16(a, b, c, 0, 0, 0);
}

// A-fragment from LDS: A[m = lane&15][k = quad*8 + j], 16B contiguous per lane
__device__ __forceinline__ f16x8 ldsA(const unsigned short* buf, int stride,
                                      int m0, int k0, int lane) {
    int row = m0 + (lane & 15);
    int col = k0 + (lane >> 4) * 8;
    return *(const f16x8*)(buf + row * stride + col);
}
// B-fragment from pre-swizzled global: tile of 64 lanes x 16B
__device__ __forceinline__ f16x8 ldB(const unsigned short* ws, int tile, int lane) {
    return *(const f16x8*)(ws + (size_t)tile * 512 + lane * 8);
}

// ---------------------------------------------------------------------------
// Weight conversion: fp32 -> fp16 in MFMA B-fragment-swizzled layout.
// (byte-identical to the R2-passing version)
// ---------------------------------------------------------------------------
__global__ __launch_bounds__(256) void convert_weights(
        const float* __restrict__ Wp, const float* __restrict__ Wg1,
        const float* __restrict__ We1, const float* __restrict__ We2,
        const float* __restrict__ We3, unsigned short* __restrict__ ws) {
    int idx = blockIdx.x * 256 + threadIdx.x;
    if (idx >= TOTAL_W) return;
    int j = idx & 7;
    int lane = (idx >> 3) & 63;
    int t = idx >> 9;
    int quad = lane >> 4, nl = lane & 15;
    int kin = quad * 8 + j;
    float val = 0.f;
    if (idx < OFF_WG1) {                 // Wp [153][153], Kp=160 Np=160
        int kt = t / 10, nt = t % 10;
        int k = kt * 32 + kin, n = nt * 16 + nl;
        if (k < 153 && n < 153) val = Wp[k * 153 + n];
    } else if (idx < OFF_WE1) {          // Wg1 [153][64]
        int tt = t - (OFF_WG1 >> 9);
        int kt = tt / 4, nt = tt % 4;
        int k = kt * 32 + kin, n = nt * 16 + nl;
        if (k < 153) val = Wg1[k * 64 + n];
    } else if (idx < OFF_WE2) {          // We1 [8][153][128]
        int tt = t - (OFF_WE1 >> 9);
        int e = tt / 40, r = tt % 40, kt = r / 8, nt = r % 8;
        int k = kt * 32 + kin, n = nt * 16 + nl;
        if (k < 153) val = We1[((size_t)e * 153 + k) * 128 + n];
    } else if (idx < OFF_WE3) {          // We2 [8][128][64]
        int tt = t - (OFF_WE2 >> 9);
        int e = tt / 16, r = tt % 16, kt = r / 4, nt = r % 4;
        int k = kt * 32 + kin, n = nt * 16 + nl;
        val = We2[((size_t)e * 128 + k) * 64 + n];
    } else {                             // We3 [8][64][8], Np=16 (cols 8..15 zero)
        int tt = t - (OFF_WE3 >> 9);
        int e = tt / 2, kt = tt % 2;
        int k = kt * 32 + kin, n = nl;
        if (n < 8) val = We3[((size_t)e * 64 + k) * 8 + n];
    }
    ws[idx] = f2h(val);
}

// ---------------------------------------------------------------------------
// Fused MoE kernel: one block = 64 rows, 4 waves.
// ONLY change vs the R2-passing kernel: xb now aliases the g1/h1 scratch
// region (xb dead after phase-2 epilogue; g1 first written after B2 barrier).
// LDS: 26624 (xb|g1/h1|g2/h2) + 21504 (xp) + 2048 (gate) = 50176 B
//   -> 3 blocks/CU at runtime (was 71680 B -> 2 blocks/CU).
// ---------------------------------------------------------------------------
__global__ __launch_bounds__(256, 2) void moe_main(
        const float* __restrict__ x,
        const float* __restrict__ ln_in_g, const float* __restrict__ ln_in_b,
        const float* __restrict__ bp,
        const float* __restrict__ bg1,
        const float* __restrict__ Wg2, const float* __restrict__ bg2,
        const float* __restrict__ Wg3, const float* __restrict__ bg3,
        const float* __restrict__ be1, const float* __restrict__ be2,
        const float* __restrict__ be3,
        const float* __restrict__ ln_out_g, const float* __restrict__ ln_out_b,
        const unsigned short* __restrict__ wsw,
        float* __restrict__ out) {
    const int tid = threadIdx.x;
    const int wave = tid >> 6, lane = tid & 63;
    const int quad = lane >> 4, nl = lane & 15;
    const size_t rowBase = (size_t)blockIdx.x * M_TILE;

    __shared__ __align__(16) char U[26624];  // xb (21504 B) -> g1/h1 (17408) + g2/h2 (9216)
    __shared__ __align__(16) unsigned short xp[M_TILE * XB_STRIDE];  // x_proj f16
    __shared__ __align__(16) float gate[M_TILE * 8];
    unsigned short* xb = (unsigned short*)U;                       // [64][168] f16
    float* g1 = (float*)U;                                         // [64][68] f32
    float* g2 = (float*)(U + 17408);                               // [64][33] f32
    unsigned short* h1 = (unsigned short*)U;                       // [64][136] f16
    unsigned short* h2 = (unsigned short*)(U + 17408);             // [64][72] f16

    const f32x4 fzero = {0.f, 0.f, 0.f, 0.f};

    // ---- Phase 1: input LayerNorm (4 threads per row) ----
    {
        int r = tid >> 2, seg = tid & 3;
        const float* xr = x + (rowBase + r) * (size_t)D_IN;
        float vals[39];
        float s = 0.f, sq = 0.f;
        #pragma unroll
        for (int i = 0; i < 39; i++) {
            int c = seg + i * 4;
            float v = (c < D_IN) ? xr[c] : 0.f;
            vals[i] = v; s += v; sq += v * v;
        }
        s += __shfl_xor(s, 1);  s += __shfl_xor(s, 2);
        sq += __shfl_xor(sq, 1); sq += __shfl_xor(sq, 2);
        float mean = s * (1.f / 153.f);
        float var = sq * (1.f / 153.f) - mean * mean;
        float rstd = rsqrtf(var + 1e-5f);
        #pragma unroll
        for (int i = 0; i < 39; i++) {
            int c = seg + i * 4;
            if (c < D_IN) {
                float v = (vals[i] - mean) * rstd * ln_in_g[c] + ln_in_b[c];
                xb[r * XB_STRIDE + c] = f2h(v);
            }
        }
        if (tid < M_TILE) {
            #pragma unroll
            for (int c = D_IN; c < XB_STRIDE; c++) xb[tid * XB_STRIDE + c] = 0;
        }
    }
    __syncthreads();

    // ---- Phase 2: x_proj = relu(x_norm @ Wp + bp) + x_norm  (M=64,N=160,K=160)
    {
        f32x4 acc[3][4];
        #pragma unroll
        for (int q = 0; q < 3; q++)
            #pragma unroll
            for (int m = 0; m < 4; m++) acc[q][m] = fzero;
        const int nnt = (wave < 2) ? 3 : 2;
        for (int kt = 0; kt < 5; kt++) {
            f16x8 a0 = ldsA(xb, XB_STRIDE, 0,  kt * 32, lane);
            f16x8 a1 = ldsA(xb, XB_STRIDE, 16, kt * 32, lane);
            f16x8 a2 = ldsA(xb, XB_STRIDE, 32, kt * 32, lane);
            f16x8 a3 = ldsA(xb, XB_STRIDE, 48, kt * 32, lane);
            #pragma unroll
            for (int q = 0; q < 3; q++) {
                if (q < nnt) {
                    int nt = wave + 4 * q;
                    f16x8 b = ldB(wsw, (OFF_WP >> 9) + kt * 10 + nt, lane);
                    acc[q][0] = mfma16(a0, b, acc[q][0]);
                    acc[q][1] = mfma16(a1, b, acc[q][1]);
                    acc[q][2] = mfma16(a2, b, acc[q][2]);
                    acc[q][3] = mfma16(a3, b, acc[q][3]);
                }
            }
        }
        #pragma unroll
        for (int q = 0; q < 3; q++) {
            if (q < nnt) {
                int nt = wave + 4 * q;
                int col = nt * 16 + nl;
                float bpv = (col < D_IN) ? bp[col] : 0.f;
                #pragma unroll
                for (int m = 0; m < 4; m++)
                    #pragma unroll
                    for (int i = 0; i < 4; i++) {
                        int row = m * 16 + quad * 4 + i;
                        float v = fmaxf(acc[q][m][i] + bpv, 0.f)
                                  + h2f(xb[row * XB_STRIDE + col]);
                        xp[row * XB_STRIDE + col] = f2h(v);
                    }
            }
        }
        if (tid < M_TILE) {
            #pragma unroll
            for (int c = 160; c < XB_STRIDE; c++) xp[tid * XB_STRIDE + c] = 0;
        }
    }
    __syncthreads();  // B2: xp ready; xb dead -> U reusable as g1/h1

    // ---- Phase 3: g1 = relu(x_proj @ Wg1 + bg1)  (M=64,N=64,K=160)
    {
        f32x4 acc[4];
        #pragma unroll
        for (int m = 0; m < 4; m++) acc[m] = fzero;
        for (int kt = 0; kt < 5; kt++) {
            f16x8 a0 = ldsA(xp, XB_STRIDE, 0,  kt * 32, lane);
            f16x8 a1 = ldsA(xp, XB_STRIDE, 16, kt * 32, lane);
            f16x8 a2 = ldsA(xp, XB_STRIDE, 32, kt * 32, lane);
            f16x8 a3 = ldsA(xp, XB_STRIDE, 48, kt * 32, lane);
            f16x8 b = ldB(wsw, (OFF_WG1 >> 9) + kt * 4 + wave, lane);
            acc[0] = mfma16(a0, b, acc[0]);
            acc[1] = mfma16(a1, b, acc[1]);
            acc[2] = mfma16(a2, b, acc[2]);
            acc[3] = mfma16(a3, b, acc[3]);
        }
        int col = wave * 16 + nl;
        float bv = bg1[col];
        #pragma unroll
        for (int m = 0; m < 4; m++)
            #pragma unroll
            for (int i = 0; i < 4; i++) {
                int row = m * 16 + quad * 4 + i;
                g1[row * G1_STRIDE + col] = fmaxf(acc[m][i] + bv, 0.f);
            }
    }
    __syncthreads();

    // ---- Phase 4: g2 = relu(g1 @ Wg2 + bg2)  vector (K=64,N=32)
    {
        int r = tid >> 2, c0 = (tid & 3) * 8;
        float s[8];
        #pragma unroll
        for (int c = 0; c < 8; c++) s[c] = bg2[c0 + c];
        for (int k = 0; k < 64; k++) {
            float gv = g1[r * G1_STRIDE + k];
            #pragma unroll
            for (int c = 0; c < 8; c++) s[c] += gv * Wg2[k * 32 + c0 + c];
        }
        #pragma unroll
        for (int c = 0; c < 8; c++) g2[r * G2_STRIDE + c0 + c] = fmaxf(s[c], 0.f);
    }
    __syncthreads();

    // ---- Phase 5: gating logits + softmax, write gating output ----
    if (tid < M_TILE) {
        int r = tid;
        float s[8];
        #pragma unroll
        for (int o = 0; o < 8; o++) s[o] = bg3[o];
        for (int k = 0; k < 32; k++) {
            float gv = g2[r * G2_STRIDE + k];
            #pragma unroll
            for (int o = 0; o < 8; o++) s[o] += gv * Wg3[k * 8 + o];
        }
        float mx = s[0];
        #pragma unroll
        for (int o = 1; o < 8; o++) mx = fmaxf(mx, s[o]);
        float sum = 0.f;
        #pragma unroll
        for (int o = 0; o < 8; o++) { s[o] = __expf(s[o] - mx); sum += s[o]; }
        float inv = 1.f / sum;
        #pragma unroll
        for (int o = 0; o < 8; o++) { s[o] *= inv; gate[r * 8 + o] = s[o]; }
        float* og = out + (size_t)B_ROWS * 8 + (rowBase + r) * 8;
        *(float4*)og       = make_float4(s[0], s[1], s[2], s[3]);
        *(float4*)(og + 4) = make_float4(s[4], s[5], s[6], s[7]);
    }
    __syncthreads();

    // ---- Phase 6: experts ----
    float oacc[4] = {0.f, 0.f, 0.f, 0.f};
    for (int e = 0; e < 8; e++) {
        // We1: h1 = relu(x_proj @ We1[e] + be1[e])  (M=64,N=128,K=160)
        {
            f32x4 acc[2][4];
            #pragma unroll
            for (int q = 0; q < 2; q++)
                #pragma unroll
                for (int m = 0; m < 4; m++) acc[q][m] = fzero;
            for (int kt = 0; kt < 5; kt++) {
                f16x8 a0 = ldsA(xp, XB_STRIDE, 0,  kt * 32, lane);
                f16x8 a1 = ldsA(xp, XB_STRIDE, 16, kt * 32, lane);
                f16x8 a2 = ldsA(xp, XB_STRIDE, 32, kt * 32, lane);
                f16x8 a3 = ldsA(xp, XB_STRIDE, 48, kt * 32, lane);
                int tb = (OFF_WE1 >> 9) + (e * 5 + kt) * 8 + wave * 2;
                f16x8 b0 = ldB(wsw, tb, lane);
                f16x8 b1 = ldB(wsw, tb + 1, lane);
                acc[0][0] = mfma16(a0, b0, acc[0][0]);
                acc[0][1] = mfma16(a1, b0, acc[0][1]);
                acc[0][2] = mfma16(a2, b0, acc[0][2]);
                acc[0][3] = mfma16(a3, b0, acc[0][3]);
                acc[1][0] = mfma16(a0, b1, acc[1][0]);
                acc[1][1] = mfma16(a1, b1, acc[1][1]);
                acc[1][2] = mfma16(a2, b1, acc[1][2]);
                acc[1][3] = mfma16(a3, b1, acc[1][3]);
            }
            #pragma unroll
            for (int q = 0; q < 2; q++) {
                int col = wave * 32 + q * 16 + nl;
                float bv = be1[e * 128 + col];
                #pragma unroll
                for (int m = 0; m < 4; m++)
                    #pragma unroll
                    for (int i = 0; i < 4; i++) {
                        int row = m * 16 + quad * 4 + i;
                        h1[row * H1_STRIDE + col] = f2h(fmaxf(acc[q][m][i] + bv, 0.f));
                    }
            }
        }
        __syncthreads();
        // We2: h2 = relu(h1 @ We2[e] + be2[e])  (M=64,N=64,K=128)
        {
            f32x4 acc[4];
            #pragma unroll
            for (int m = 0; m < 4; m++) acc[m] = fzero;
            for (int kt = 0; kt < 4; kt++) {
                f16x8 a0 = ldsA(h1, H1_STRIDE, 0,  kt * 32, lane);
                f16x8 a1 = ldsA(h1, H1_STRIDE, 16, kt * 32, lane);
                f16x8 a2 = ldsA(h1, H1_STRIDE, 32, kt * 32, lane);
                f16x8 a3 = ldsA(h1, H1_STRIDE, 48, kt * 32, lane);
                f16x8 b = ldB(wsw, (OFF_WE2 >> 9) + (e * 4 + kt) * 4 + wave, lane);
                acc[0] = mfma16(a0, b, acc[0]);
                acc[1] = mfma16(a1, b, acc[1]);
                acc[2] = mfma16(a2, b, acc[2]);
                acc[3] = mfma16(a3, b, acc[3]);
            }
            int col = wave * 16 + nl;
            float bv = be2[e * 64 + col];
            #pragma unroll
            for (int m = 0; m < 4; m++)
                #pragma unroll
                for (int i = 0; i < 4; i++) {
                    int row = m * 16 + quad * 4 + i;
                    h2[row * H2_STRIDE + col] = f2h(fmaxf(acc[m][i] + bv, 0.f));
                }
        }
        __syncthreads();
        // We3 + gated accumulate  (per wave: rows wave*16..+15; M=16,N=16(8),K=64)
        {
            f32x4 acc = fzero;
            #pragma unroll
            for (int kt = 0; kt < 2; kt++) {
                f16x8 a = ldsA(h2, H2_STRIDE, wave * 16, kt * 32, lane);
                f16x8 b = ldB(wsw, (OFF_WE3 >> 9) + e * 2 + kt, lane);
                acc = mfma16(a, b, acc);
            }
            if (nl < 8) {
                float bv = be3[e * 8 + nl];
                #pragma unroll
                for (int i = 0; i < 4; i++) {
                    int row = wave * 16 + quad * 4 + i;
                    oacc[i] += gate[row * 8 + e] * (acc[i] + bv);
                }
            }
        }
        __syncthreads();
    }

    // ---- Phase 7: output LayerNorm over 8 + store ----
    {
        float go = 1.f, bo = 0.f;
        if (nl < 8) { go = ln_out_g[nl]; bo = ln_out_b[nl]; }
        #pragma unroll
        for (int i = 0; i < 4; i++) {
            float v = oacc[i];
            float s = v + __shfl_xor(v, 1);
            s += __shfl_xor(s, 2);
            s += __shfl_xor(s, 4);
            float q2 = v * v;
            float q = q2 + __shfl_xor(q2, 1);
            q += __shfl_xor(q, 2);
            q += __shfl_xor(q, 4);
            float mean = s * 0.125f;
            float var = q * 0.125f - mean * mean;
            float rstd = rsqrtf(var + 1e-5f);
            float ov = (v - mean) * rstd * go + bo;
            if (nl < 8) {
                size_t row = rowBase + wave * 16 + quad * 4 + i;
                out[row * 8 + nl] = ov;
            }
        }
    }
}

extern "C" void kernel_launch(void* const* d_in, const int* in_sizes, int n_in,
                              void* d_out, int out_size, void* d_ws, size_t ws_size,
                              hipStream_t stream) {
    const float* x        = (const float*)d_in[0];
    const float* ln_in_g  = (const float*)d_in[1];
    const float* ln_in_b  = (const float*)d_in[2];
    const float* Wp       = (const float*)d_in[3];
    const float* bp       = (const float*)d_in[4];
    const float* Wg1      = (const float*)d_in[5];
    const float* bg1      = (const float*)d_in[6];
    const float* Wg2      = (const float*)d_in[7];
    const float* bg2      = (const float*)d_in[8];
    const float* Wg3      = (const float*)d_in[9];
    const float* bg3      = (const float*)d_in[10];
    const float* We1      = (const float*)d_in[11];
    const float* be1      = (const float*)d_in[12];
    const float* We2      = (const float*)d_in[13];
    const float* be2      = (const float*)d_in[14];
    const float* We3      = (const float*)d_in[15];
    const float* be3      = (const float*)d_in[16];
    const float* ln_out_g = (const float*)d_in[17];
    const float* ln_out_b = (const float*)d_in[18];
    unsigned short* ws = (unsigned short*)d_ws;
    float* out = (float*)d_out;

    convert_weights<<<(TOTAL_W + 255) / 256, 256, 0, stream>>>(
        Wp, Wg1, We1, We2, We3, ws);
    moe_main<<<B_ROWS / M_TILE, 256, 0, stream>>>(
        x, ln_in_g, ln_in_b, bp, bg1, Wg2, bg2, Wg3, bg3,
        be1, be2, be3, ln_out_g, ln_out_b, ws, out);
}

// Round 7
// 431.768 us; speedup vs baseline: 1.1917x; 1.0993x over previous
//
#include <hip/hip_runtime.h>
#include <stdint.h>
#include <stddef.h>

typedef __attribute__((ext_vector_type(8))) _Float16 f16x8;
typedef __attribute__((ext_vector_type(4))) float f32x4;

#define D_IN 153
#define B_ROWS 262144
#define M_TILE 64
#define XB_STRIDE 168
#define G1H_STRIDE 68
#define H1_STRIDE 136
#define H2_STRIDE 72

// swizzled f16 weight layout offsets (in u16 elements, all multiples of 512)
#define OFF_WP 0
#define SZ_WP (5*10*512)
#define OFF_WG1 (OFF_WP + SZ_WP)
#define SZ_WG1 (5*4*512)
#define OFF_WE1 (OFF_WG1 + SZ_WG1)
#define SZ_WE1 (8*5*8*512)
#define OFF_WE2 (OFF_WE1 + SZ_WE1)
#define SZ_WE2 (8*4*4*512)
#define OFF_WE3 (OFF_WE2 + SZ_WE2)
#define SZ_WE3 (8*2*512)
#define OFF_WG2 (OFF_WE3 + SZ_WE3)
#define SZ_WG2 (2*2*512)
#define OFF_WG3 (OFF_WG2 + SZ_WG2)
#define SZ_WG3 (1*512)
#define TOTAL_W (OFF_WG3 + SZ_WG3)   // 275968 u16 = 551936 B

__device__ __forceinline__ unsigned short f2h(float f) {
    _Float16 h = (_Float16)f;                 // v_cvt_f16_f32, RNE
    union { _Float16 h; unsigned short u; } v; v.h = h;
    return v.u;
}
__device__ __forceinline__ float h2f(unsigned short u) {
    union { unsigned short u; _Float16 h; } v; v.u = u;
    return (float)v.h;
}

__device__ __forceinline__ f32x4 mfma16(f16x8 a, f16x8 b, f32x4 c) {
    return __builtin_amdgcn_mfma_f32_16x16x32_f16(a, b, c, 0, 0, 0);
}

// A-fragment from LDS: A[m = lane&15][k = quad*8 + j], 16B contiguous per lane
__device__ __forceinline__ f16x8 ldsA(const unsigned short* buf, int stride,
                                      int m0, int k0, int lane) {
    int row = m0 + (lane & 15);
    int col = k0 + (lane >> 4) * 8;
    return *(const f16x8*)(buf + row * stride + col);
}
// B-fragment from pre-swizzled global: tile of 64 lanes x 16B
__device__ __forceinline__ f16x8 ldB(const unsigned short* ws, int tile, int lane) {
    return *(const f16x8*)(ws + (size_t)tile * 512 + lane * 8);
}

// ---------------------------------------------------------------------------
// Weight conversion: fp32 -> fp16 in MFMA B-fragment-swizzled layout.
// (R2/R6-identical for Wp..We3; adds Wg2 [64][32] and Wg3 [32][8] tiles.)
// ---------------------------------------------------------------------------
__global__ __launch_bounds__(256) void convert_weights(
        const float* __restrict__ Wp, const float* __restrict__ Wg1,
        const float* __restrict__ We1, const float* __restrict__ We2,
        const float* __restrict__ We3, const float* __restrict__ Wg2,
        const float* __restrict__ Wg3, unsigned short* __restrict__ ws) {
    int idx = blockIdx.x * 256 + threadIdx.x;
    if (idx >= TOTAL_W) return;
    int j = idx & 7;
    int lane = (idx >> 3) & 63;
    int t = idx >> 9;
    int quad = lane >> 4, nl = lane & 15;
    int kin = quad * 8 + j;
    float val = 0.f;
    if (idx < OFF_WG1) {                 // Wp [153][153], Kp=160 Np=160
        int kt = t / 10, nt = t % 10;
        int k = kt * 32 + kin, n = nt * 16 + nl;
        if (k < 153 && n < 153) val = Wp[k * 153 + n];
    } else if (idx < OFF_WE1) {          // Wg1 [153][64]
        int tt = t - (OFF_WG1 >> 9);
        int kt = tt / 4, nt = tt % 4;
        int k = kt * 32 + kin, n = nt * 16 + nl;
        if (k < 153) val = Wg1[k * 64 + n];
    } else if (idx < OFF_WE2) {          // We1 [8][153][128]
        int tt = t - (OFF_WE1 >> 9);
        int e = tt / 40, r = tt % 40, kt = r / 8, nt = r % 8;
        int k = kt * 32 + kin, n = nt * 16 + nl;
        if (k < 153) val = We1[((size_t)e * 153 + k) * 128 + n];
    } else if (idx < OFF_WE3) {          // We2 [8][128][64]
        int tt = t - (OFF_WE2 >> 9);
        int e = tt / 16, r = tt % 16, kt = r / 4, nt = r % 4;
        int k = kt * 32 + kin, n = nt * 16 + nl;
        val = We2[((size_t)e * 128 + k) * 64 + n];
    } else if (idx < OFF_WG2) {          // We3 [8][64][8], Np=16 (cols 8..15 zero)
        int tt = t - (OFF_WE3 >> 9);
        int e = tt / 2, kt = tt % 2;
        int k = kt * 32 + kin, n = nl;
        if (n < 8) val = We3[((size_t)e * 64 + k) * 8 + n];
    } else if (idx < OFF_WG3) {          // Wg2 [64][32]
        int tt = t - (OFF_WG2 >> 9);
        int kt = tt >> 1, nt = tt & 1;
        int k = kt * 32 + kin, n = nt * 16 + nl;
        val = Wg2[k * 32 + n];
    } else {                             // Wg3 [32][8] (cols 8..15 zero)
        int k = kin, n = nl;
        if (n < 8) val = Wg3[k * 8 + n];
    }
    ws[idx] = f2h(val);
}

// ---------------------------------------------------------------------------
// Fused MoE kernel: one block = 64 rows, 4 waves, 3 blocks/CU.
// ONLY change vs R6-passing kernel: phases 4+5 (gating MLP) now run on MFMA
// (per-wave 16 rows), g1 stored as f16 row-major; Wg2/Wg3 pre-swizzled.
// LDS unchanged: 26624 (U) + 21504 (xp) + 2048 (gate) = 50176 B.
// ---------------------------------------------------------------------------
__global__ __launch_bounds__(256, 2) void moe_main(
        const float* __restrict__ x,
        const float* __restrict__ ln_in_g, const float* __restrict__ ln_in_b,
        const float* __restrict__ bp,
        const float* __restrict__ bg1, const float* __restrict__ bg2,
        const float* __restrict__ bg3,
        const float* __restrict__ be1, const float* __restrict__ be2,
        const float* __restrict__ be3,
        const float* __restrict__ ln_out_g, const float* __restrict__ ln_out_b,
        const unsigned short* __restrict__ wsw,
        float* __restrict__ out) {
    const int tid = threadIdx.x;
    const int wave = tid >> 6, lane = tid & 63;
    const int quad = lane >> 4, nl = lane & 15;
    const size_t rowBase = (size_t)blockIdx.x * M_TILE;

    __shared__ __align__(16) char U[26624];  // xb -> g1h/g2s -> h1|h2
    __shared__ __align__(16) unsigned short xp[M_TILE * XB_STRIDE];  // x_proj f16
    __shared__ __align__(16) float gate[M_TILE * 8];
    unsigned short* xb  = (unsigned short*)U;              // [64][168] f16
    unsigned short* g1h = (unsigned short*)U;              // [64][68]  f16 (8704 B)
    unsigned short* g2s = (unsigned short*)(U + 17408);    // 4 x 512 u16 A-frags
    unsigned short* h1  = (unsigned short*)U;              // [64][136] f16
    unsigned short* h2  = (unsigned short*)(U + 17408);    // [64][72]  f16

    const f32x4 fzero = {0.f, 0.f, 0.f, 0.f};

    // ---- Phase 1: input LayerNorm (4 threads per row) ----
    {
        int r = tid >> 2, seg = tid & 3;
        const float* xr = x + (rowBase + r) * (size_t)D_IN;
        float vals[39];
        float s = 0.f, sq = 0.f;
        #pragma unroll
        for (int i = 0; i < 39; i++) {
            int c = seg + i * 4;
            float v = (c < D_IN) ? xr[c] : 0.f;
            vals[i] = v; s += v; sq += v * v;
        }
        s += __shfl_xor(s, 1);  s += __shfl_xor(s, 2);
        sq += __shfl_xor(sq, 1); sq += __shfl_xor(sq, 2);
        float mean = s * (1.f / 153.f);
        float var = sq * (1.f / 153.f) - mean * mean;
        float rstd = rsqrtf(var + 1e-5f);
        #pragma unroll
        for (int i = 0; i < 39; i++) {
            int c = seg + i * 4;
            if (c < D_IN) {
                float v = (vals[i] - mean) * rstd * ln_in_g[c] + ln_in_b[c];
                xb[r * XB_STRIDE + c] = f2h(v);
            }
        }
        if (tid < M_TILE) {
            #pragma unroll
            for (int c = D_IN; c < XB_STRIDE; c++) xb[tid * XB_STRIDE + c] = 0;
        }
    }
    __syncthreads();

    // ---- Phase 2: x_proj = relu(x_norm @ Wp + bp) + x_norm  (M=64,N=160,K=160)
    {
        f32x4 acc[3][4];
        #pragma unroll
        for (int q = 0; q < 3; q++)
            #pragma unroll
            for (int m = 0; m < 4; m++) acc[q][m] = fzero;
        const int nnt = (wave < 2) ? 3 : 2;
        for (int kt = 0; kt < 5; kt++) {
            f16x8 a0 = ldsA(xb, XB_STRIDE, 0,  kt * 32, lane);
            f16x8 a1 = ldsA(xb, XB_STRIDE, 16, kt * 32, lane);
            f16x8 a2 = ldsA(xb, XB_STRIDE, 32, kt * 32, lane);
            f16x8 a3 = ldsA(xb, XB_STRIDE, 48, kt * 32, lane);
            #pragma unroll
            for (int q = 0; q < 3; q++) {
                if (q < nnt) {
                    int nt = wave + 4 * q;
                    f16x8 b = ldB(wsw, (OFF_WP >> 9) + kt * 10 + nt, lane);
                    acc[q][0] = mfma16(a0, b, acc[q][0]);
                    acc[q][1] = mfma16(a1, b, acc[q][1]);
                    acc[q][2] = mfma16(a2, b, acc[q][2]);
                    acc[q][3] = mfma16(a3, b, acc[q][3]);
                }
            }
        }
        #pragma unroll
        for (int q = 0; q < 3; q++) {
            if (q < nnt) {
                int nt = wave + 4 * q;
                int col = nt * 16 + nl;
                float bpv = (col < D_IN) ? bp[col] : 0.f;
                #pragma unroll
                for (int m = 0; m < 4; m++)
                    #pragma unroll
                    for (int i = 0; i < 4; i++) {
                        int row = m * 16 + quad * 4 + i;
                        float v = fmaxf(acc[q][m][i] + bpv, 0.f)
                                  + h2f(xb[row * XB_STRIDE + col]);
                        xp[row * XB_STRIDE + col] = f2h(v);
                    }
            }
        }
        if (tid < M_TILE) {
            #pragma unroll
            for (int c = 160; c < XB_STRIDE; c++) xp[tid * XB_STRIDE + c] = 0;
        }
    }
    __syncthreads();  // B2: xp ready; xb dead -> U reusable as g1h

    // ---- Phase 3: g1 = relu(x_proj @ Wg1 + bg1) -> f16 row-major (M=64,N=64,K=160)
    {
        f32x4 acc[4];
        #pragma unroll
        for (int m = 0; m < 4; m++) acc[m] = fzero;
        for (int kt = 0; kt < 5; kt++) {
            f16x8 a0 = ldsA(xp, XB_STRIDE, 0,  kt * 32, lane);
            f16x8 a1 = ldsA(xp, XB_STRIDE, 16, kt * 32, lane);
            f16x8 a2 = ldsA(xp, XB_STRIDE, 32, kt * 32, lane);
            f16x8 a3 = ldsA(xp, XB_STRIDE, 48, kt * 32, lane);
            f16x8 b = ldB(wsw, (OFF_WG1 >> 9) + kt * 4 + wave, lane);
            acc[0] = mfma16(a0, b, acc[0]);
            acc[1] = mfma16(a1, b, acc[1]);
            acc[2] = mfma16(a2, b, acc[2]);
            acc[3] = mfma16(a3, b, acc[3]);
        }
        int col = wave * 16 + nl;
        float bv = bg1[col];
        #pragma unroll
        for (int m = 0; m < 4; m++)
            #pragma unroll
            for (int i = 0; i < 4; i++) {
                int row = m * 16 + quad * 4 + i;
                g1h[row * G1H_STRIDE + col] = f2h(fmaxf(acc[m][i] + bv, 0.f));
            }
    }
    __syncthreads();  // B3: g1h ready

    // ---- Phase 4: g2 = relu(g1 @ Wg2 + bg2) via MFMA (per-wave 16 rows; M=16,N=32,K=64)
    {
        f16x8 a0 = ldsA(g1h, G1H_STRIDE, wave * 16, 0,  lane);
        f16x8 a1 = ldsA(g1h, G1H_STRIDE, wave * 16, 32, lane);
        f32x4 accg[2] = {fzero, fzero};
        #pragma unroll
        for (int nt = 0; nt < 2; nt++) {
            accg[nt] = mfma16(a0, ldB(wsw, (OFF_WG2 >> 9) + 0 * 2 + nt, lane), accg[nt]);
            accg[nt] = mfma16(a1, ldB(wsw, (OFF_WG2 >> 9) + 1 * 2 + nt, lane), accg[nt]);
        }
        // repack C (col=nl+16*nt, row=quad*4+i) -> wave-private 16x32 A-frag
        unsigned short* g2w = g2s + wave * 512;
        #pragma unroll
        for (int nt = 0; nt < 2; nt++) {
            float bv = bg2[nt * 16 + nl];
            #pragma unroll
            for (int i = 0; i < 4; i++) {
                int col = nt * 16 + nl;
                int row = quad * 4 + i;
                int off = (col >> 3) * 128 + row * 8 + (col & 7);
                g2w[off] = f2h(fmaxf(accg[nt][i] + bv, 0.f));
            }
        }
    }
    __syncthreads();  // B4a: g2s ready

    // ---- Phase 5: logits = g2 @ Wg3 + bg3 via MFMA + softmax (per-wave 16 rows)
    {
        f16x8 ag2 = *(const f16x8*)(g2s + wave * 512 + lane * 8);
        f32x4 lg = mfma16(ag2, ldB(wsw, (OFF_WG3 >> 9), lane), fzero);
        float bg3v = (nl < 8) ? bg3[nl] : 0.f;
        #pragma unroll
        for (int i = 0; i < 4; i++) {
            float v = lg[i] + bg3v;
            float m = v;
            m = fmaxf(m, __shfl_xor(m, 1));
            m = fmaxf(m, __shfl_xor(m, 2));
            m = fmaxf(m, __shfl_xor(m, 4));
            float e = __expf(v - m);
            float ssum = e + __shfl_xor(e, 1);
            ssum += __shfl_xor(ssum, 2);
            ssum += __shfl_xor(ssum, 4);
            float g = e / ssum;
            if (nl < 8) {
                int row = wave * 16 + quad * 4 + i;
                gate[row * 8 + nl] = g;
                out[(size_t)B_ROWS * 8 + (rowBase + row) * 8 + nl] = g;
            }
        }
    }
    __syncthreads();  // B4: gate ready; U region free for h1/h2

    // ---- Phase 6: experts (unchanged from R6) ----
    float oacc[4] = {0.f, 0.f, 0.f, 0.f};
    for (int e = 0; e < 8; e++) {
        // We1: h1 = relu(x_proj @ We1[e] + be1[e])  (M=64,N=128,K=160)
        {
            f32x4 acc[2][4];
            #pragma unroll
            for (int q = 0; q < 2; q++)
                #pragma unroll
                for (int m = 0; m < 4; m++) acc[q][m] = fzero;
            for (int kt = 0; kt < 5; kt++) {
                f16x8 a0 = ldsA(xp, XB_STRIDE, 0,  kt * 32, lane);
                f16x8 a1 = ldsA(xp, XB_STRIDE, 16, kt * 32, lane);
                f16x8 a2 = ldsA(xp, XB_STRIDE, 32, kt * 32, lane);
                f16x8 a3 = ldsA(xp, XB_STRIDE, 48, kt * 32, lane);
                int tb = (OFF_WE1 >> 9) + (e * 5 + kt) * 8 + wave * 2;
                f16x8 b0 = ldB(wsw, tb, lane);
                f16x8 b1 = ldB(wsw, tb + 1, lane);
                acc[0][0] = mfma16(a0, b0, acc[0][0]);
                acc[0][1] = mfma16(a1, b0, acc[0][1]);
                acc[0][2] = mfma16(a2, b0, acc[0][2]);
                acc[0][3] = mfma16(a3, b0, acc[0][3]);
                acc[1][0] = mfma16(a0, b1, acc[1][0]);
                acc[1][1] = mfma16(a1, b1, acc[1][1]);
                acc[1][2] = mfma16(a2, b1, acc[1][2]);
                acc[1][3] = mfma16(a3, b1, acc[1][3]);
            }
            #pragma unroll
            for (int q = 0; q < 2; q++) {
                int col = wave * 32 + q * 16 + nl;
                float bv = be1[e * 128 + col];
                #pragma unroll
                for (int m = 0; m < 4; m++)
                    #pragma unroll
                    for (int i = 0; i < 4; i++) {
                        int row = m * 16 + quad * 4 + i;
                        h1[row * H1_STRIDE + col] = f2h(fmaxf(acc[q][m][i] + bv, 0.f));
                    }
            }
        }
        __syncthreads();
        // We2: h2 = relu(h1 @ We2[e] + be2[e])  (M=64,N=64,K=128)
        {
            f32x4 acc[4];
            #pragma unroll
            for (int m = 0; m < 4; m++) acc[m] = fzero;
            for (int kt = 0; kt < 4; kt++) {
                f16x8 a0 = ldsA(h1, H1_STRIDE, 0,  kt * 32, lane);
                f16x8 a1 = ldsA(h1, H1_STRIDE, 16, kt * 32, lane);
                f16x8 a2 = ldsA(h1, H1_STRIDE, 32, kt * 32, lane);
                f16x8 a3 = ldsA(h1, H1_STRIDE, 48, kt * 32, lane);
                f16x8 b = ldB(wsw, (OFF_WE2 >> 9) + (e * 4 + kt) * 4 + wave, lane);
                acc[0] = mfma16(a0, b, acc[0]);
                acc[1] = mfma16(a1, b, acc[1]);
                acc[2] = mfma16(a2, b, acc[2]);
                acc[3] = mfma16(a3, b, acc[3]);
            }
            int col = wave * 16 + nl;
            float bv = be2[e * 64 + col];
            #pragma unroll
            for (int m = 0; m < 4; m++)
                #pragma unroll
                for (int i = 0; i < 4; i++) {
                    int row = m * 16 + quad * 4 + i;
                    h2[row * H2_STRIDE + col] = f2h(fmaxf(acc[m][i] + bv, 0.f));
                }
        }
        __syncthreads();
        // We3 + gated accumulate  (per wave: rows wave*16..+15; M=16,N=16(8),K=64)
        {
            f32x4 acc = fzero;
            #pragma unroll
            for (int kt = 0; kt < 2; kt++) {
                f16x8 a = ldsA(h2, H2_STRIDE, wave * 16, kt * 32, lane);
                f16x8 b = ldB(wsw, (OFF_WE3 >> 9) + e * 2 + kt, lane);
                acc = mfma16(a, b, acc);
            }
            if (nl < 8) {
                float bv = be3[e * 8 + nl];
                #pragma unroll
                for (int i = 0; i < 4; i++) {
                    int row = wave * 16 + quad * 4 + i;
                    oacc[i] += gate[row * 8 + e] * (acc[i] + bv);
                }
            }
        }
        __syncthreads();
    }

    // ---- Phase 7: output LayerNorm over 8 + store ----
    {
        float go = 1.f, bo = 0.f;
        if (nl < 8) { go = ln_out_g[nl]; bo = ln_out_b[nl]; }
        #pragma unroll
        for (int i = 0; i < 4; i++) {
            float v = oacc[i];
            float s = v + __shfl_xor(v, 1);
            s += __shfl_xor(s, 2);
            s += __shfl_xor(s, 4);
            float q2 = v * v;
            float q = q2 + __shfl_xor(q2, 1);
            q += __shfl_xor(q, 2);
            q += __shfl_xor(q, 4);
            float mean = s * 0.125f;
            float var = q * 0.125f - mean * mean;
            float rstd = rsqrtf(var + 1e-5f);
            float ov = (v - mean) * rstd * go + bo;
            if (nl < 8) {
                size_t row = rowBase + wave * 16 + quad * 4 + i;
                out[row * 8 + nl] = ov;
            }
        }
    }
}

extern "C" void kernel_launch(void* const* d_in, const int* in_sizes, int n_in,
                              void* d_out, int out_size, void* d_ws, size_t ws_size,
                              hipStream_t stream) {
    const float* x        = (const float*)d_in[0];
    const float* ln_in_g  = (const float*)d_in[1];
    const float* ln_in_b  = (const float*)d_in[2];
    const float* Wp       = (const float*)d_in[3];
    const float* bp       = (const float*)d_in[4];
    const float* Wg1      = (const float*)d_in[5];
    const float* bg1      = (const float*)d_in[6];
    const float* Wg2      = (const float*)d_in[7];
    const float* bg2      = (const float*)d_in[8];
    const float* Wg3      = (const float*)d_in[9];
    const float* bg3      = (const float*)d_in[10];
    const float* We1      = (const float*)d_in[11];
    const float* be1      = (const float*)d_in[12];
    const float* We2      = (const float*)d_in[13];
    const float* be2      = (const float*)d_in[14];
    const float* We3      = (const float*)d_in[15];
    const float* be3      = (const float*)d_in[16];
    const float* ln_out_g = (const float*)d_in[17];
    const float* ln_out_b = (const float*)d_in[18];
    unsigned short* ws = (unsigned short*)d_ws;
    float* out = (float*)d_out;

    convert_weights<<<(TOTAL_W + 255) / 256, 256, 0, stream>>>(
        Wp, Wg1, We1, We2, We3, Wg2, Wg3, ws);
    moe_main<<<B_ROWS / M_TILE, 256, 0, stream>>>(
        x, ln_in_g, ln_in_b, bp, bg1, bg2, bg3,
        be1, be2, be3, ln_out_g, ln_out_b, ws, out);
}

// Round 8
// 427.111 us; speedup vs baseline: 1.2047x; 1.0109x over previous
//
#include <hip/hip_runtime.h>
#include <stdint.h>
#include <stddef.h>

typedef __attribute__((ext_vector_type(8))) _Float16 f16x8;
typedef __attribute__((ext_vector_type(4))) float f32x4;

#define D_IN 153
#define B_ROWS 262144
#define M_TILE 64
#define XB_STRIDE 168
#define G1H_STRIDE 68
#define H1_STRIDE 136
#define H2_STRIDE 72

// swizzled f16 weight layout offsets (in u16 elements, all multiples of 512)
#define OFF_WP 0
#define SZ_WP (5*10*512)
#define OFF_WG1 (OFF_WP + SZ_WP)
#define SZ_WG1 (5*4*512)
#define OFF_WE1 (OFF_WG1 + SZ_WG1)
#define SZ_WE1 (8*5*8*512)
#define OFF_WE2 (OFF_WE1 + SZ_WE1)
#define SZ_WE2 (8*4*4*512)
#define OFF_WE3 (OFF_WE2 + SZ_WE2)
#define SZ_WE3 (8*2*512)
#define OFF_WG2 (OFF_WE3 + SZ_WE3)
#define SZ_WG2 (2*2*512)
#define OFF_WG3 (OFF_WG2 + SZ_WG2)
#define SZ_WG3 (1*512)
#define TOTAL_W (OFF_WG3 + SZ_WG3)   // 275968 u16 = 551936 B

__device__ __forceinline__ unsigned short f2h(float f) {
    _Float16 h = (_Float16)f;                 // v_cvt_f16_f32, RNE
    union { _Float16 h; unsigned short u; } v; v.h = h;
    return v.u;
}
__device__ __forceinline__ float h2f(unsigned short u) {
    union { unsigned short u; _Float16 h; } v; v.u = u;
    return (float)v.h;
}

__device__ __forceinline__ f32x4 mfma16(f16x8 a, f16x8 b, f32x4 c) {
    return __builtin_amdgcn_mfma_f32_16x16x32_f16(a, b, c, 0, 0, 0);
}

// A-fragment from LDS: A[m = lane&15][k = quad*8 + j], 16B contiguous per lane
__device__ __forceinline__ f16x8 ldsA(const unsigned short* buf, int stride,
                                      int m0, int k0, int lane) {
    int row = m0 + (lane & 15);
    int col = k0 + (lane >> 4) * 8;
    return *(const f16x8*)(buf + row * stride + col);
}
// B-fragment from pre-swizzled global: tile of 64 lanes x 16B
__device__ __forceinline__ f16x8 ldB(const unsigned short* ws, int tile, int lane) {
    return *(const f16x8*)(ws + (size_t)tile * 512 + lane * 8);
}

// ---------------------------------------------------------------------------
// Weight conversion: fp32 -> fp16 in MFMA B-fragment-swizzled layout.
// (identical to R7-passing version)
// ---------------------------------------------------------------------------
__global__ __launch_bounds__(256) void convert_weights(
        const float* __restrict__ Wp, const float* __restrict__ Wg1,
        const float* __restrict__ We1, const float* __restrict__ We2,
        const float* __restrict__ We3, const float* __restrict__ Wg2,
        const float* __restrict__ Wg3, unsigned short* __restrict__ ws) {
    int idx = blockIdx.x * 256 + threadIdx.x;
    if (idx >= TOTAL_W) return;
    int j = idx & 7;
    int lane = (idx >> 3) & 63;
    int t = idx >> 9;
    int quad = lane >> 4, nl = lane & 15;
    int kin = quad * 8 + j;
    float val = 0.f;
    if (idx < OFF_WG1) {                 // Wp [153][153], Kp=160 Np=160
        int kt = t / 10, nt = t % 10;
        int k = kt * 32 + kin, n = nt * 16 + nl;
        if (k < 153 && n < 153) val = Wp[k * 153 + n];
    } else if (idx < OFF_WE1) {          // Wg1 [153][64]
        int tt = t - (OFF_WG1 >> 9);
        int kt = tt / 4, nt = tt % 4;
        int k = kt * 32 + kin, n = nt * 16 + nl;
        if (k < 153) val = Wg1[k * 64 + n];
    } else if (idx < OFF_WE2) {          // We1 [8][153][128]
        int tt = t - (OFF_WE1 >> 9);
        int e = tt / 40, r = tt % 40, kt = r / 8, nt = r % 8;
        int k = kt * 32 + kin, n = nt * 16 + nl;
        if (k < 153) val = We1[((size_t)e * 153 + k) * 128 + n];
    } else if (idx < OFF_WE3) {          // We2 [8][128][64]
        int tt = t - (OFF_WE2 >> 9);
        int e = tt / 16, r = tt % 16, kt = r / 4, nt = r % 4;
        int k = kt * 32 + kin, n = nt * 16 + nl;
        val = We2[((size_t)e * 128 + k) * 64 + n];
    } else if (idx < OFF_WG2) {          // We3 [8][64][8], Np=16 (cols 8..15 zero)
        int tt = t - (OFF_WE3 >> 9);
        int e = tt / 2, kt = tt % 2;
        int k = kt * 32 + kin, n = nl;
        if (n < 8) val = We3[((size_t)e * 64 + k) * 8 + n];
    } else if (idx < OFF_WG3) {          // Wg2 [64][32]
        int tt = t - (OFF_WG2 >> 9);
        int kt = tt >> 1, nt = tt & 1;
        int k = kt * 32 + kin, n = nt * 16 + nl;
        val = Wg2[k * 32 + n];
    } else {                             // Wg3 [32][8] (cols 8..15 zero)
        int k = kin, n = nl;
        if (n < 8) val = Wg3[k * 8 + n];
    }
    ws[idx] = f2h(val);
}

// ---------------------------------------------------------------------------
// Fused MoE kernel: one block = 64 rows, 4 waves, 3 blocks/CU.
// ONLY change vs R7-passing kernel: removed the redundant end-of-expert-loop
// __syncthreads (Be3). Hazards: h1 WAR protected by Be2; h2 WAR protected by
// the NEXT iteration's Be1; gate/xp read-only in loop. 29 -> 21 barriers.
// ---------------------------------------------------------------------------
__global__ __launch_bounds__(256, 2) void moe_main(
        const float* __restrict__ x,
        const float* __restrict__ ln_in_g, const float* __restrict__ ln_in_b,
        const float* __restrict__ bp,
        const float* __restrict__ bg1, const float* __restrict__ bg2,
        const float* __restrict__ bg3,
        const float* __restrict__ be1, const float* __restrict__ be2,
        const float* __restrict__ be3,
        const float* __restrict__ ln_out_g, const float* __restrict__ ln_out_b,
        const unsigned short* __restrict__ wsw,
        float* __restrict__ out) {
    const int tid = threadIdx.x;
    const int wave = tid >> 6, lane = tid & 63;
    const int quad = lane >> 4, nl = lane & 15;
    const size_t rowBase = (size_t)blockIdx.x * M_TILE;

    __shared__ __align__(16) char U[26624];  // xb -> g1h/g2s -> h1|h2
    __shared__ __align__(16) unsigned short xp[M_TILE * XB_STRIDE];  // x_proj f16
    __shared__ __align__(16) float gate[M_TILE * 8];
    unsigned short* xb  = (unsigned short*)U;              // [64][168] f16
    unsigned short* g1h = (unsigned short*)U;              // [64][68]  f16 (8704 B)
    unsigned short* g2s = (unsigned short*)(U + 17408);    // 4 x 512 u16 A-frags
    unsigned short* h1  = (unsigned short*)U;              // [64][136] f16
    unsigned short* h2  = (unsigned short*)(U + 17408);    // [64][72]  f16

    const f32x4 fzero = {0.f, 0.f, 0.f, 0.f};

    // ---- Phase 1: input LayerNorm (4 threads per row) ----
    {
        int r = tid >> 2, seg = tid & 3;
        const float* xr = x + (rowBase + r) * (size_t)D_IN;
        float vals[39];
        float s = 0.f, sq = 0.f;
        #pragma unroll
        for (int i = 0; i < 39; i++) {
            int c = seg + i * 4;
            float v = (c < D_IN) ? xr[c] : 0.f;
            vals[i] = v; s += v; sq += v * v;
        }
        s += __shfl_xor(s, 1);  s += __shfl_xor(s, 2);
        sq += __shfl_xor(sq, 1); sq += __shfl_xor(sq, 2);
        float mean = s * (1.f / 153.f);
        float var = sq * (1.f / 153.f) - mean * mean;
        float rstd = rsqrtf(var + 1e-5f);
        #pragma unroll
        for (int i = 0; i < 39; i++) {
            int c = seg + i * 4;
            if (c < D_IN) {
                float v = (vals[i] - mean) * rstd * ln_in_g[c] + ln_in_b[c];
                xb[r * XB_STRIDE + c] = f2h(v);
            }
        }
        if (tid < M_TILE) {
            #pragma unroll
            for (int c = D_IN; c < XB_STRIDE; c++) xb[tid * XB_STRIDE + c] = 0;
        }
    }
    __syncthreads();

    // ---- Phase 2: x_proj = relu(x_norm @ Wp + bp) + x_norm  (M=64,N=160,K=160)
    {
        f32x4 acc[3][4];
        #pragma unroll
        for (int q = 0; q < 3; q++)
            #pragma unroll
            for (int m = 0; m < 4; m++) acc[q][m] = fzero;
        const int nnt = (wave < 2) ? 3 : 2;
        for (int kt = 0; kt < 5; kt++) {
            f16x8 a0 = ldsA(xb, XB_STRIDE, 0,  kt * 32, lane);
            f16x8 a1 = ldsA(xb, XB_STRIDE, 16, kt * 32, lane);
            f16x8 a2 = ldsA(xb, XB_STRIDE, 32, kt * 32, lane);
            f16x8 a3 = ldsA(xb, XB_STRIDE, 48, kt * 32, lane);
            #pragma unroll
            for (int q = 0; q < 3; q++) {
                if (q < nnt) {
                    int nt = wave + 4 * q;
                    f16x8 b = ldB(wsw, (OFF_WP >> 9) + kt * 10 + nt, lane);
                    acc[q][0] = mfma16(a0, b, acc[q][0]);
                    acc[q][1] = mfma16(a1, b, acc[q][1]);
                    acc[q][2] = mfma16(a2, b, acc[q][2]);
                    acc[q][3] = mfma16(a3, b, acc[q][3]);
                }
            }
        }
        #pragma unroll
        for (int q = 0; q < 3; q++) {
            if (q < nnt) {
                int nt = wave + 4 * q;
                int col = nt * 16 + nl;
                float bpv = (col < D_IN) ? bp[col] : 0.f;
                #pragma unroll
                for (int m = 0; m < 4; m++)
                    #pragma unroll
                    for (int i = 0; i < 4; i++) {
                        int row = m * 16 + quad * 4 + i;
                        float v = fmaxf(acc[q][m][i] + bpv, 0.f)
                                  + h2f(xb[row * XB_STRIDE + col]);
                        xp[row * XB_STRIDE + col] = f2h(v);
                    }
            }
        }
        if (tid < M_TILE) {
            #pragma unroll
            for (int c = 160; c < XB_STRIDE; c++) xp[tid * XB_STRIDE + c] = 0;
        }
    }
    __syncthreads();  // B2: xp ready; xb dead -> U reusable as g1h

    // ---- Phase 3: g1 = relu(x_proj @ Wg1 + bg1) -> f16 row-major (M=64,N=64,K=160)
    {
        f32x4 acc[4];
        #pragma unroll
        for (int m = 0; m < 4; m++) acc[m] = fzero;
        for (int kt = 0; kt < 5; kt++) {
            f16x8 a0 = ldsA(xp, XB_STRIDE, 0,  kt * 32, lane);
            f16x8 a1 = ldsA(xp, XB_STRIDE, 16, kt * 32, lane);
            f16x8 a2 = ldsA(xp, XB_STRIDE, 32, kt * 32, lane);
            f16x8 a3 = ldsA(xp, XB_STRIDE, 48, kt * 32, lane);
            f16x8 b = ldB(wsw, (OFF_WG1 >> 9) + kt * 4 + wave, lane);
            acc[0] = mfma16(a0, b, acc[0]);
            acc[1] = mfma16(a1, b, acc[1]);
            acc[2] = mfma16(a2, b, acc[2]);
            acc[3] = mfma16(a3, b, acc[3]);
        }
        int col = wave * 16 + nl;
        float bv = bg1[col];
        #pragma unroll
        for (int m = 0; m < 4; m++)
            #pragma unroll
            for (int i = 0; i < 4; i++) {
                int row = m * 16 + quad * 4 + i;
                g1h[row * G1H_STRIDE + col] = f2h(fmaxf(acc[m][i] + bv, 0.f));
            }
    }
    __syncthreads();  // B3: g1h ready

    // ---- Phase 4: g2 = relu(g1 @ Wg2 + bg2) via MFMA (per-wave 16 rows; M=16,N=32,K=64)
    {
        f16x8 a0 = ldsA(g1h, G1H_STRIDE, wave * 16, 0,  lane);
        f16x8 a1 = ldsA(g1h, G1H_STRIDE, wave * 16, 32, lane);
        f32x4 accg[2] = {fzero, fzero};
        #pragma unroll
        for (int nt = 0; nt < 2; nt++) {
            accg[nt] = mfma16(a0, ldB(wsw, (OFF_WG2 >> 9) + 0 * 2 + nt, lane), accg[nt]);
            accg[nt] = mfma16(a1, ldB(wsw, (OFF_WG2 >> 9) + 1 * 2 + nt, lane), accg[nt]);
        }
        // repack C (col=nl+16*nt, row=quad*4+i) -> wave-private 16x32 A-frag
        unsigned short* g2w = g2s + wave * 512;
        #pragma unroll
        for (int nt = 0; nt < 2; nt++) {
            float bv = bg2[nt * 16 + nl];
            #pragma unroll
            for (int i = 0; i < 4; i++) {
                int col = nt * 16 + nl;
                int row = quad * 4 + i;
                int off = (col >> 3) * 128 + row * 8 + (col & 7);
                g2w[off] = f2h(fmaxf(accg[nt][i] + bv, 0.f));
            }
        }
    }
    __syncthreads();  // B4a: g2s ready

    // ---- Phase 5: logits = g2 @ Wg3 + bg3 via MFMA + softmax (per-wave 16 rows)
    {
        f16x8 ag2 = *(const f16x8*)(g2s + wave * 512 + lane * 8);
        f32x4 lg = mfma16(ag2, ldB(wsw, (OFF_WG3 >> 9), lane), fzero);
        float bg3v = (nl < 8) ? bg3[nl] : 0.f;
        #pragma unroll
        for (int i = 0; i < 4; i++) {
            float v = lg[i] + bg3v;
            float m = v;
            m = fmaxf(m, __shfl_xor(m, 1));
            m = fmaxf(m, __shfl_xor(m, 2));
            m = fmaxf(m, __shfl_xor(m, 4));
            float e = __expf(v - m);
            float ssum = e + __shfl_xor(e, 1);
            ssum += __shfl_xor(ssum, 2);
            ssum += __shfl_xor(ssum, 4);
            float g = e / ssum;
            if (nl < 8) {
                int row = wave * 16 + quad * 4 + i;
                gate[row * 8 + nl] = g;
                out[(size_t)B_ROWS * 8 + (rowBase + row) * 8 + nl] = g;
            }
        }
    }
    __syncthreads();  // B4: gate ready; U region free for h1/h2

    // ---- Phase 6: experts (2 barriers per expert; end-of-loop barrier removed)
    float oacc[4] = {0.f, 0.f, 0.f, 0.f};
    for (int e = 0; e < 8; e++) {
        // We1: h1 = relu(x_proj @ We1[e] + be1[e])  (M=64,N=128,K=160)
        {
            f32x4 acc[2][4];
            #pragma unroll
            for (int q = 0; q < 2; q++)
                #pragma unroll
                for (int m = 0; m < 4; m++) acc[q][m] = fzero;
            for (int kt = 0; kt < 5; kt++) {
                f16x8 a0 = ldsA(xp, XB_STRIDE, 0,  kt * 32, lane);
                f16x8 a1 = ldsA(xp, XB_STRIDE, 16, kt * 32, lane);
                f16x8 a2 = ldsA(xp, XB_STRIDE, 32, kt * 32, lane);
                f16x8 a3 = ldsA(xp, XB_STRIDE, 48, kt * 32, lane);
                int tb = (OFF_WE1 >> 9) + (e * 5 + kt) * 8 + wave * 2;
                f16x8 b0 = ldB(wsw, tb, lane);
                f16x8 b1 = ldB(wsw, tb + 1, lane);
                acc[0][0] = mfma16(a0, b0, acc[0][0]);
                acc[0][1] = mfma16(a1, b0, acc[0][1]);
                acc[0][2] = mfma16(a2, b0, acc[0][2]);
                acc[0][3] = mfma16(a3, b0, acc[0][3]);
                acc[1][0] = mfma16(a0, b1, acc[1][0]);
                acc[1][1] = mfma16(a1, b1, acc[1][1]);
                acc[1][2] = mfma16(a2, b1, acc[1][2]);
                acc[1][3] = mfma16(a3, b1, acc[1][3]);
            }
            #pragma unroll
            for (int q = 0; q < 2; q++) {
                int col = wave * 32 + q * 16 + nl;
                float bv = be1[e * 128 + col];
                #pragma unroll
                for (int m = 0; m < 4; m++)
                    #pragma unroll
                    for (int i = 0; i < 4; i++) {
                        int row = m * 16 + quad * 4 + i;
                        h1[row * H1_STRIDE + col] = f2h(fmaxf(acc[q][m][i] + bv, 0.f));
                    }
            }
        }
        __syncthreads();  // Be1: h1 ready (also orders prev We3 h2-reads before h2-writes)
        // We2: h2 = relu(h1 @ We2[e] + be2[e])  (M=64,N=64,K=128)
        {
            f32x4 acc[4];
            #pragma unroll
            for (int m = 0; m < 4; m++) acc[m] = fzero;
            for (int kt = 0; kt < 4; kt++) {
                f16x8 a0 = ldsA(h1, H1_STRIDE, 0,  kt * 32, lane);
                f16x8 a1 = ldsA(h1, H1_STRIDE, 16, kt * 32, lane);
                f16x8 a2 = ldsA(h1, H1_STRIDE, 32, kt * 32, lane);
                f16x8 a3 = ldsA(h1, H1_STRIDE, 48, kt * 32, lane);
                f16x8 b = ldB(wsw, (OFF_WE2 >> 9) + (e * 4 + kt) * 4 + wave, lane);
                acc[0] = mfma16(a0, b, acc[0]);
                acc[1] = mfma16(a1, b, acc[1]);
                acc[2] = mfma16(a2, b, acc[2]);
                acc[3] = mfma16(a3, b, acc[3]);
            }
            int col = wave * 16 + nl;
            float bv = be2[e * 64 + col];
            #pragma unroll
            for (int m = 0; m < 4; m++)
                #pragma unroll
                for (int i = 0; i < 4; i++) {
                    int row = m * 16 + quad * 4 + i;
                    h2[row * H2_STRIDE + col] = f2h(fmaxf(acc[m][i] + bv, 0.f));
                }
        }
        __syncthreads();  // Be2: h2 ready (also orders all h1-reads before next h1-writes)
        // We3 + gated accumulate  (per wave: rows wave*16..+15; M=16,N=16(8),K=64)
        {
            f32x4 acc = fzero;
            #pragma unroll
            for (int kt = 0; kt < 2; kt++) {
                f16x8 a = ldsA(h2, H2_STRIDE, wave * 16, kt * 32, lane);
                f16x8 b = ldB(wsw, (OFF_WE3 >> 9) + e * 2 + kt, lane);
                acc = mfma16(a, b, acc);
            }
            if (nl < 8) {
                float bv = be3[e * 8 + nl];
                #pragma unroll
                for (int i = 0; i < 4; i++) {
                    int row = wave * 16 + quad * 4 + i;
                    oacc[i] += gate[row * 8 + e] * (acc[i] + bv);
                }
            }
        }
        // (no end-of-loop barrier: h1 WAR covered by Be2, h2 WAR by next Be1)
    }

    // ---- Phase 7: output LayerNorm over 8 + store ----
    {
        float go = 1.f, bo = 0.f;
        if (nl < 8) { go = ln_out_g[nl]; bo = ln_out_b[nl]; }
        #pragma unroll
        for (int i = 0; i < 4; i++) {
            float v = oacc[i];
            float s = v + __shfl_xor(v, 1);
            s += __shfl_xor(s, 2);
            s += __shfl_xor(s, 4);
            float q2 = v * v;
            float q = q2 + __shfl_xor(q2, 1);
            q += __shfl_xor(q, 2);
            q += __shfl_xor(q, 4);
            float mean = s * 0.125f;
            float var = q * 0.125f - mean * mean;
            float rstd = rsqrtf(var + 1e-5f);
            float ov = (v - mean) * rstd * go + bo;
            if (nl < 8) {
                size_t row = rowBase + wave * 16 + quad * 4 + i;
                out[row * 8 + nl] = ov;
            }
        }
    }
}

extern "C" void kernel_launch(void* const* d_in, const int* in_sizes, int n_in,
                              void* d_out, int out_size, void* d_ws, size_t ws_size,
                              hipStream_t stream) {
    const float* x        = (const float*)d_in[0];
    const float* ln_in_g  = (const float*)d_in[1];
    const float* ln_in_b  = (const float*)d_in[2];
    const float* Wp       = (const float*)d_in[3];
    const float* bp       = (const float*)d_in[4];
    const float* Wg1      = (const float*)d_in[5];
    const float* bg1      = (const float*)d_in[6];
    const float* Wg2      = (const float*)d_in[7];
    const float* bg2      = (const float*)d_in[8];
    const float* Wg3      = (const float*)d_in[9];
    const float* bg3      = (const float*)d_in[10];
    const float* We1      = (const float*)d_in[11];
    const float* be1      = (const float*)d_in[12];
    const float* We2      = (const float*)d_in[13];
    const float* be2      = (const float*)d_in[14];
    const float* We3      = (const float*)d_in[15];
    const float* be3      = (const float*)d_in[16];
    const float* ln_out_g = (const float*)d_in[17];
    const float* ln_out_b = (const float*)d_in[18];
    unsigned short* ws = (unsigned short*)d_ws;
    float* out = (float*)d_out;

    convert_weights<<<(TOTAL_W + 255) / 256, 256, 0, stream>>>(
        Wp, Wg1, We1, We2, We3, Wg2, Wg3, ws);
    moe_main<<<B_ROWS / M_TILE, 256, 0, stream>>>(
        x, ln_in_g, ln_in_b, bp, bg1, bg2, bg3,
        be1, be2, be3, ln_out_g, ln_out_b, ws, out);
}